// Round 1
// baseline (219.093 us; speedup 1.0000x reference)
//
#include <hip/hip_runtime.h>

#define HH 320
#define WW 320
#define NIMG 8      // B(4) * channels(2)
#define BIGF 1.0e5f

// Kernel 1: vertical 1D distance per column. One thread per (n, w) column.
// n = b*2 + c (channel folded into batch, matching moveaxis(zero,-1,1)).
// Down sweep writes running distance-to-seed-above; up sweep combines with
// distance-to-seed-below, squares, stores g2 into ws.
__global__ void edt_vert(const float* __restrict__ in, float* __restrict__ g2) {
    int idx = blockIdx.x * blockDim.x + threadIdx.x;
    if (idx >= NIMG * WW) return;
    int n = idx / WW;
    int w = idx - n * WW;
    int b = n >> 1;
    int c = n & 1;
    // input index for (b,h,w,c): ((b*H + h)*W + w)*2 + c
    const float* ip = in + (size_t)b * HH * WW * 2 + (size_t)w * 2 + c;
    float* gp = g2 + (size_t)n * HH * WW + w;

    float cnt = BIGF;
    for (int h = 0; h < HH; ++h) {
        float x = ip[(size_t)h * WW * 2];
        bool z = (1.0f - x) * 127.5f < 1.0f;   // uint8 truncation == 0
        cnt = z ? 0.0f : fminf(cnt + 1.0f, BIGF);
        gp[(size_t)h * WW] = cnt;
    }
    cnt = BIGF;
    for (int h = HH - 1; h >= 0; --h) {
        float x = ip[(size_t)h * WW * 2];
        bool z = (1.0f - x) * 127.5f < 1.0f;
        cnt = z ? 0.0f : fminf(cnt + 1.0f, BIGF);
        float g = fminf(gp[(size_t)h * WW], cnt);
        gp[(size_t)h * WW] = g * g;
    }
}

// Kernel 2: exact horizontal lower envelope (brute force over source column x)
// + Gaussian epilogue. One block per row (n, h); 320 threads, thread j = dest col.
__global__ __launch_bounds__(WW) void edt_horiz(const float* __restrict__ g2,
                                                float* __restrict__ out) {
    int row = blockIdx.x;          // [0, NIMG*H)
    int n = row / HH;
    int h = row - n * HH;
    int b = n >> 1;
    int c = n & 1;

    __shared__ float sg[WW];
    int j = threadIdx.x;
    sg[j] = g2[(size_t)row * WW + j];
    __syncthreads();

    float fj = (float)j;
    float d2 = 3.4e38f;
    #pragma unroll 8
    for (int x = 0; x < WW; ++x) {
        float t = fj - (float)x;
        d2 = fminf(d2, fmaf(t, t, sg[x]));   // same-address LDS broadcast
    }

    // out[b,h,j, c*3 + s] : flat ((b*H + h)*W + j)*6 + c*3 + s
    float* op = out + (((size_t)b * HH + h) * WW + j) * 6 + (size_t)c * 3;
    op[0] = __expf(-d2 * (1.0f / 81.92f));    // 2*(0.02*320)^2
    op[1] = __expf(-d2 * (1.0f / 1310.72f));  // 2*(0.08*320)^2
    op[2] = __expf(-d2 * (1.0f / 5242.88f));  // 2*(0.16*320)^2
}

extern "C" void kernel_launch(void* const* d_in, const int* in_sizes, int n_in,
                              void* d_out, int out_size, void* d_ws, size_t ws_size,
                              hipStream_t stream) {
    const float* in = (const float*)d_in[0];
    float* out = (float*)d_out;
    float* g2 = (float*)d_ws;   // NIMG*H*W floats = 3.27 MB scratch

    edt_vert<<<(NIMG * WW + 255) / 256, 256, 0, stream>>>(in, g2);
    edt_horiz<<<NIMG * HH, WW, 0, stream>>>(g2, out);
}

// Round 2
// 79.819 us; speedup vs baseline: 2.7449x; 2.7449x over previous
//
#include <hip/hip_runtime.h>

#define HH 320
#define WW 320
#define NIMG 8      // B(4) * channels(2)
#define BIGF 1.0e5f

#define CH 20       // h rows per thread (vert)
#define NCH 16      // h chunks per column (CH*NCH = 320)
#define WT 64       // columns per vert block

// Kernel 1: vertical 1D distance, chunked parallel scan.
// Block: (64 cols, 16 chunks) = 1024 threads; grid: 8 imgs * 5 col-tiles = 40.
// Each thread scans CH=20 rows of one column; chunk summaries (last/next seed
// index) combine via LDS; then exact per-row distances, capped at BIG, squared.
__global__ __launch_bounds__(1024) void edt_vert(const float* __restrict__ in,
                                                 float* __restrict__ g2) {
    int wl = threadIdx.x;            // 0..63 column within tile (wave = one chunk)
    int ch = threadIdx.y;            // 0..15 h-chunk
    int img = blockIdx.x / 5;
    int wt  = blockIdx.x % 5;
    int w = wt * WT + wl;
    int b = img >> 1, c = img & 1;
    int h0 = ch * CH;

    const float* ip = in + ((size_t)(b * HH + h0) * WW + w) * 2 + c;
    unsigned mask = 0;
    #pragma unroll
    for (int k = 0; k < CH; ++k) {
        float x = ip[(size_t)k * WW * 2];
        if ((1.0f - x) * 127.5f < 1.0f) mask |= 1u << k;   // uint8 restore == 0
    }

    __shared__ float sLast[NCH][WT];
    __shared__ float sNxt[NCH][WT];
    float lastLoc = mask ? (float)(h0 + 31 - __clz((int)mask)) : -1.0e9f;
    float nxtLoc  = mask ? (float)(h0 + __ffs((int)mask) - 1)  :  1.0e9f;
    sLast[ch][wl] = lastLoc;
    sNxt[ch][wl]  = nxtLoc;
    __syncthreads();

    float inc = -1.0e9f, incN = 1.0e9f;          // exclusive combine across chunks
    for (int cc = 0; cc < ch; ++cc)        inc  = fmaxf(inc,  sLast[cc][wl]);
    for (int cc = ch + 1; cc < NCH; ++cc)  incN = fminf(incN, sNxt[cc][wl]);

    float gd[CH];
    float runLast = inc;
    #pragma unroll
    for (int k = 0; k < CH; ++k) {
        if (mask & (1u << k)) runLast = (float)(h0 + k);
        gd[k] = (float)(h0 + k) - runLast;       // dist to seed above (exact int)
    }
    float runNxt = incN;
    float* gp = g2 + ((size_t)img * HH + h0) * WW + w;
    #pragma unroll
    for (int k = CH - 1; k >= 0; --k) {
        if (mask & (1u << k)) runNxt = (float)(h0 + k);
        float g = fminf(fminf(gd[k], runNxt - (float)(h0 + k)), BIGF);
        gp[(size_t)k * WW] = g * g;
    }
}

// Kernel 2: exact horizontal lower envelope + Gaussian epilogue.
// Block: 256 threads = 4 waves; each wave owns one row (no cross-wave LDS
// traffic -> no barrier). Each lane owns 5 dest columns j = lane + 64m
// (5 independent min chains). Row g2 staged in LDS, read as broadcast float4:
// one ds_read_b128 per 20 fma+min.
__global__ __launch_bounds__(256) void edt_horiz(const float* __restrict__ g2,
                                                 float* __restrict__ out) {
    int wv   = threadIdx.x >> 6;
    int lane = threadIdx.x & 63;
    int row  = blockIdx.x * 4 + wv;      // n*H + h, < 2560
    int n = row / HH;
    int h = row - n * HH;
    int b = n >> 1, c = n & 1;

    __shared__ __align__(16) float sg[4][WW];
    const float* grow = g2 + (size_t)row * WW;
    #pragma unroll
    for (int m = 0; m < 5; ++m) sg[wv][lane + 64 * m] = grow[lane + 64 * m];
    // same-wave LDS write->read: in-order per wave, compiler inserts lgkmcnt

    float d2v[5], tb[5];
    #pragma unroll
    for (int m = 0; m < 5; ++m) {
        d2v[m] = 3.4e38f;
        tb[m]  = (float)(lane + 64 * m);  // t = j - x, decremented per x
    }

    const float4* sv = (const float4*)sg[wv];
    for (int xc = 0; xc < WW / 4; ++xc) {
        float4 g4 = sv[xc];               // same-address broadcast, conflict-free
        float gk[4] = {g4.x, g4.y, g4.z, g4.w};
        #pragma unroll
        for (int k = 0; k < 4; ++k) {
            #pragma unroll
            for (int m = 0; m < 5; ++m) {
                float t = tb[m];
                d2v[m] = fminf(d2v[m], fmaf(t, t, gk[k]));  // t^2 exact int
                tb[m] = t - 1.0f;
            }
        }
    }

    // out[b,h,j, c*3 + s] : flat ((b*H + h)*W + j)*6 + c*3
    float* op = out + (((size_t)b * HH + h) * WW + lane) * 6 + (size_t)c * 3;
    #pragma unroll
    for (int m = 0; m < 5; ++m) {
        float d2 = d2v[m];
        float* q = op + (size_t)m * 64 * 6;
        q[0] = __expf(-d2 * (1.0f / 81.92f));    // 2*(0.02*320)^2
        q[1] = __expf(-d2 * (1.0f / 1310.72f));  // 2*(0.08*320)^2
        q[2] = __expf(-d2 * (1.0f / 5242.88f));  // 2*(0.16*320)^2
    }
}

extern "C" void kernel_launch(void* const* d_in, const int* in_sizes, int n_in,
                              void* d_out, int out_size, void* d_ws, size_t ws_size,
                              hipStream_t stream) {
    const float* in = (const float*)d_in[0];
    float* out = (float*)d_out;
    float* g2 = (float*)d_ws;   // NIMG*H*W floats = 3.27 MB scratch

    edt_vert<<<NIMG * (WW / WT), dim3(WT, NCH), 0, stream>>>(in, g2);
    edt_horiz<<<NIMG * HH / 4, 256, 0, stream>>>(g2, out);
}

// Round 3
// 75.148 us; speedup vs baseline: 2.9155x; 1.0622x over previous
//
#include <hip/hip_runtime.h>

#define HH 320
#define WW 320
#define NIMG 8      // B(4) * channels(2)
#define BIGF 1.0e5f

// ---- Kernel 1: vertical 1D distance, chunked parallel scan, float2 loads ----
// Thread handles CH=10 rows of one column for BOTH channels (coalesced float2).
// Block (16 w, 32 chunks) = 512 threads; grid = 4 b * 20 col-tiles = 80 blocks.
#define TW  16
#define NCH 32
#define CH  10

__global__ __launch_bounds__(512) void edt_vert(const float* __restrict__ in,
                                                float* __restrict__ g2) {
    int wl = threadIdx.x;            // 0..15 column within tile
    int ch = threadIdx.y;            // 0..31 h-chunk
    int b  = blockIdx.x / 20;
    int wt = blockIdx.x % 20;
    int w  = wt * TW + wl;
    int h0 = ch * CH;

    const float2* ip = (const float2*)in + (size_t)(b * HH + h0) * WW + w;
    float2 v[CH];
    #pragma unroll
    for (int k = 0; k < CH; ++k) v[k] = ip[(size_t)k * WW];

    unsigned m0 = 0, m1 = 0;
    #pragma unroll
    for (int k = 0; k < CH; ++k) {
        if ((1.0f - v[k].x) * 127.5f < 1.0f) m0 |= 1u << k;  // uint8 restore == 0
        if ((1.0f - v[k].y) * 127.5f < 1.0f) m1 |= 1u << k;
    }

    __shared__ float sL[2][NCH][TW], sN[2][NCH][TW];
    sL[0][ch][wl] = m0 ? (float)(h0 + 31 - __clz((int)m0)) : -1.0e9f;
    sL[1][ch][wl] = m1 ? (float)(h0 + 31 - __clz((int)m1)) : -1.0e9f;
    sN[0][ch][wl] = m0 ? (float)(h0 + __ffs((int)m0) - 1)  :  1.0e9f;
    sN[1][ch][wl] = m1 ? (float)(h0 + __ffs((int)m1) - 1)  :  1.0e9f;
    __syncthreads();

    // exclusive combine across chunks (predicated, wave-uniform trip count)
    float L0 = -1.0e9f, L1 = -1.0e9f, N0 = 1.0e9f, N1 = 1.0e9f;
    for (int cc = 0; cc < NCH; ++cc) {
        float a0 = sL[0][cc][wl], a1 = sL[1][cc][wl];
        float b0 = sN[0][cc][wl], b1 = sN[1][cc][wl];
        if (cc < ch) { L0 = fmaxf(L0, a0); L1 = fmaxf(L1, a1); }
        if (cc > ch) { N0 = fminf(N0, b0); N1 = fminf(N1, b1); }
    }

    float gd0[CH], gd1[CH];
    float r0 = L0, r1 = L1;
    #pragma unroll
    for (int k = 0; k < CH; ++k) {
        float fh = (float)(h0 + k);
        if (m0 & (1u << k)) r0 = fh;
        if (m1 & (1u << k)) r1 = fh;
        gd0[k] = fh - r0;            // dist to seed above (exact int or ~1e9)
        gd1[k] = fh - r1;
    }
    float* gp0 = g2 + ((size_t)(b * 2 + 0) * HH + h0) * WW + w;
    float* gp1 = g2 + ((size_t)(b * 2 + 1) * HH + h0) * WW + w;
    r0 = N0; r1 = N1;
    #pragma unroll
    for (int k = CH - 1; k >= 0; --k) {
        float fh = (float)(h0 + k);
        if (m0 & (1u << k)) r0 = fh;
        if (m1 & (1u << k)) r1 = fh;
        float g0 = fminf(fminf(gd0[k], r0 - fh), BIGF);
        float g1 = fminf(fminf(gd1[k], r1 - fh), BIGF);
        gp0[(size_t)k * WW] = g0 * g0;
        gp1[(size_t)k * WW] = g1 * g1;
    }
}

// ---- Kernel 2: exact horizontal lower envelope + Gaussian epilogue ----
// One wave per row; lane owns 5 dest cols j = lane + 64m.
// a[x] = x^2 + g2[x] staged in LDS; inner: d2 = min(d2, fma(-2j, x, a[x])),
// final d2 += j^2. Exact integers < 2^24 in the non-capped region -> bit-exact.
// Two float4s consumed per iter, prefetched one iter ahead (hides LDS latency).
__global__ __launch_bounds__(256) void edt_horiz(const float* __restrict__ g2,
                                                 float* __restrict__ out) {
    int wv   = threadIdx.x >> 6;
    int lane = threadIdx.x & 63;
    int row  = blockIdx.x * 4 + wv;      // n*H + h
    int n = row / HH;
    int h = row - n * HH;
    int b = n >> 1, c = n & 1;

    __shared__ __align__(16) float sa[4][WW + 8];   // +8 pad: safe prefetch tail
    const float* grow = g2 + (size_t)row * WW;
    #pragma unroll
    for (int m = 0; m < 5; ++m) {
        int x = lane + 64 * m;
        float fx = (float)x;
        sa[wv][x] = fmaf(fx, fx, grow[x]);          // a[x] = x^2 + g2[x]
    }
    if (lane < 8) sa[wv][WW + lane] = 3.0e38f;      // pad: never wins the min
    // same-wave LDS write->read: in-order per wave

    float n2j[5], d2v[5];
    #pragma unroll
    for (int m = 0; m < 5; ++m) {
        n2j[m] = -2.0f * (float)(lane + 64 * m);
        d2v[m] = 3.4e38f;
    }

    const float4* sv = (const float4*)sa[wv];
    float4 c0 = sv[0], c1 = sv[1];
    for (int xc = 0; xc < WW / 4; xc += 2) {
        float4 p0 = sv[xc + 2], p1 = sv[xc + 3];    // prefetch next pair
        float av[8] = {c0.x, c0.y, c0.z, c0.w, c1.x, c1.y, c1.z, c1.w};
        float base = (float)(4 * xc);
        #pragma unroll
        for (int k = 0; k < 8; k += 2) {
            float x0 = base + (float)k;
            float x1 = base + (float)(k + 1);
            #pragma unroll
            for (int m = 0; m < 5; ++m) {
                float t0 = fmaf(n2j[m], x0, av[k]);
                float t1 = fmaf(n2j[m], x1, av[k + 1]);
                d2v[m] = fminf(d2v[m], fminf(t0, t1));   // -> v_min3_f32
            }
        }
        c0 = p0; c1 = p1;
    }

    // out[b,h,j, c*3 + s] : flat ((b*H + h)*W + j)*6 + c*3
    float* op = out + (((size_t)b * HH + h) * WW + lane) * 6 + (size_t)c * 3;
    #pragma unroll
    for (int m = 0; m < 5; ++m) {
        float fj = (float)(lane + 64 * m);
        float d2 = fmaf(fj, fj, d2v[m]);            // + j^2, exact
        float* q = op + (size_t)m * 64 * 6;
        q[0] = __expf(-d2 * (1.0f / 81.92f));       // 2*(0.02*320)^2
        q[1] = __expf(-d2 * (1.0f / 1310.72f));     // 2*(0.08*320)^2
        q[2] = __expf(-d2 * (1.0f / 5242.88f));     // 2*(0.16*320)^2
    }
}

extern "C" void kernel_launch(void* const* d_in, const int* in_sizes, int n_in,
                              void* d_out, int out_size, void* d_ws, size_t ws_size,
                              hipStream_t stream) {
    const float* in = (const float*)d_in[0];
    float* out = (float*)d_out;
    float* g2 = (float*)d_ws;   // NIMG*H*W floats = 3.27 MB scratch

    edt_vert<<<4 * 20, dim3(TW, NCH), 0, stream>>>(in, g2);
    edt_horiz<<<NIMG * HH / 4, 256, 0, stream>>>(g2, out);
}